// Round 4
// baseline (513.272 us; speedup 1.0000x reference)
//
#include <hip/hip_runtime.h>
#include <hip/hip_bf16.h>

#define B_ 32
#define T_ 4096
#define F_ 512
#define H_ 512

typedef float floatx4 __attribute__((ext_vector_type(4)));
typedef short short8 __attribute__((ext_vector_type(8)));

__device__ __forceinline__ unsigned short f2bf16(float a) {
  unsigned ua = __float_as_uint(a);
  return (unsigned short)((ua + 0x7FFFu + ((ua >> 16) & 1u)) >> 16);
}

// tanh(x) = 1 - 2/(e^{2x}+1); graceful at +/-inf.
__device__ __forceinline__ float tanh_fast(float x) {
  float e = __expf(2.0f * x);
  return 1.0f - __fdividef(2.0f, e + 1.0f);
}

// 8x fp32 -> 8x bf16 (RNE) via compiler-fused v_cvt_pk_bf16_f32 (m240).
__device__ __forceinline__ short8 cvt8(float4 lo, float4 hi) {
  union { short8 s8; __hip_bfloat16 h[8]; } u;
  u.h[0] = __float2bfloat16(lo.x);
  u.h[1] = __float2bfloat16(lo.y);
  u.h[2] = __float2bfloat16(lo.z);
  u.h[3] = __float2bfloat16(lo.w);
  u.h[4] = __float2bfloat16(hi.x);
  u.h[5] = __float2bfloat16(hi.y);
  u.h[6] = __float2bfloat16(hi.z);
  u.h[7] = __float2bfloat16(hi.w);
  return u.s8;
}

// ---- merged prep: W1 transpose->bf16 + w2d = dec@W2 + scores=0 (one dispatch)
// blocks [0,256): 32x32 transpose tiles of W1 -> W1T bf16
// blocks [256,272): w2d[b][h] over 16384 (b,h) pairs
// blocks [272,288): zero the 512KB scores accumulator (replaces hipMemsetAsync)
__global__ __launch_bounds__(1024) void prep_all(const float* __restrict__ W1,
                                                 unsigned short* __restrict__ W1T,
                                                 const float* __restrict__ dec,
                                                 const float* __restrict__ W2,
                                                 float* __restrict__ w2d,
                                                 float* __restrict__ scores) {
  __shared__ float tile[32][33];
  if (blockIdx.x < 256) {
    const int tx = threadIdx.x & 31, ty = threadIdx.x >> 5;
    const int bx = blockIdx.x & 15, by = blockIdx.x >> 4;
    const int f = by * 32 + ty;
    const int h = bx * 32 + tx;
    tile[ty][tx] = W1[f * H_ + h];
    __syncthreads();
    const int ho = bx * 32 + ty;
    const int fo = by * 32 + tx;
    W1T[ho * F_ + fo] = f2bf16(tile[tx][ty]);
  } else if (blockIdx.x < 272) {
    const int g = (blockIdx.x - 256) * 1024 + threadIdx.x;  // 16 blocks * 1024
    const int b = g >> 9;
    const int h = g & 511;
    float s0 = 0.f, s1 = 0.f, s2 = 0.f, s3 = 0.f;
    for (int f = 0; f < F_; f += 4) {
      s0 += dec[b * F_ + f + 0] * W2[(f + 0) * H_ + h];
      s1 += dec[b * F_ + f + 1] * W2[(f + 1) * H_ + h];
      s2 += dec[b * F_ + f + 2] * W2[(f + 2) * H_ + h];
      s3 += dec[b * F_ + f + 3] * W2[(f + 3) * H_ + h];
    }
    w2d[b * H_ + h] = (s0 + s1) + (s2 + s3);
  } else {
    const int g = (blockIdx.x - 272) * 1024 + threadIdx.x;
    const float4 z = {0.f, 0.f, 0.f, 0.f};
    ((float4*)scores)[g * 2 + 0] = z;
    ((float4*)scores)[g * 2 + 1] = z;
  }
}

// ---- main: fused (enc@W1) -> tanh(+w2d) -> .V row-reduce -> atomic scores ----
// Round-4 structure (T3/T4 port): triple-buffered Bs via global_load_lds with
// COUNTED vmcnt across raw s_barrier — B for step t+1 issued at t-1, so it has
// a full step of latency; the barrier never drains vmcnt to 0 in steady state.
// A stays on the verified VGPR->cvt_pk->ds_write path (round-2 lesson: pure
// register pipelines get sunk by the scheduler; here asm "memory" fences pin
// the loads inside their step).
// Bs bank swizzle FIXED (round-3 post-mortem): slot = quad ^ ((row>>1)&3)
// (source chunk c = (lane&3) ^ ((lane>>3)&3)) -> each quarter-wave hits 8
// distinct 16B bank-groups x 2 lanes = conflict-free (old row&3 version was
// 4 lanes/group = the 1.26e7 conflict cycles).
// XCD-swizzled grid: xcd = bid&7; i = bid>>3; n_blk = i&3; m_blk = xcd + 8*(i>>2)
__global__ __launch_bounds__(256, 3) void fused_score(
    const float* __restrict__ enc, const unsigned short* __restrict__ W1T,
    const float* __restrict__ w2d, const float* __restrict__ V,
    float* __restrict__ scores) {
  // As padded to 40 shorts/row (80B stride: odd multiple of 16B -> reads spread
  // across all 8 bank-groups). Bs rows 32 shorts, chunk-swizzled (see above).
  __shared__ __align__(16) unsigned short As[2][128 * 40];
  __shared__ __align__(16) unsigned short Bs[3][128 * 32];

  const int tid = threadIdx.x;
  const int bid = blockIdx.x;
  const int xcd = bid & 7;
  const int ii = bid >> 3;
  const int n_blk = ii & 3;
  const int m_blk = xcd + ((ii >> 2) << 3);
  const int lane = tid & 63;
  const int wave = tid >> 6;
  const int wm = wave >> 1;
  const int wn = wave & 1;
  const int quad = lane >> 4;
  const int l16 = lane & 15;

  // A staging: thread covers 8 consecutive floats in rows {arow, arow+64}
  const int arow = tid >> 2;       // 0..63
  const int acol = (tid & 3) * 8;  // float offset within 32-wide k-chunk
  const float* aptr = enc + (size_t)(m_blk * 128 + arow) * F_ + acol;

  // B staging via global_load_lds: dst wave-uniform base + lane*16B (linear).
  // Source pre-swizzled: LDS slot s of row n holds chunk s ^ ((n>>1)&3).
  const int nb0 = wave * 32;
  const int bl_n = lane >> 2;
  const int bl_c = (lane & 3) ^ ((lane >> 3) & 3);
  const unsigned short* bsrc0 =
      W1T + (size_t)(n_blk * 128 + nb0 + bl_n) * F_ + bl_c * 8;
  const unsigned short* bsrc1 = bsrc0 + 16 * F_;

  floatx4 acc[4][4];
#pragma unroll
  for (int i = 0; i < 4; i++)
#pragma unroll
    for (int j = 0; j < 4; j++) acc[i][j] = (floatx4){0.f, 0.f, 0.f, 0.f};

  float4 a_pre[4];

#define GLDS(SRC, DST)                                                       \
  __builtin_amdgcn_global_load_lds(                                          \
      (const __attribute__((address_space(1))) void*)(SRC),                  \
      (__attribute__((address_space(3))) void*)(DST), 16, 0, 0)

  // ---- prologue: A chunk 0 -> As[0]; B chunks 0,1 -> Bs[0],Bs[1] ----
#pragma unroll
  for (int rr = 0; rr < 2; ++rr) {
    a_pre[rr * 2 + 0] = *(const float4*)(aptr + rr * 64 * F_ + 0);
    a_pre[rr * 2 + 1] = *(const float4*)(aptr + rr * 64 * F_ + 4);
  }
  GLDS(bsrc0, &Bs[0][nb0 * 32]);
  GLDS(bsrc1, &Bs[0][(nb0 + 16) * 32]);
  GLDS(bsrc0 + 32, &Bs[1][nb0 * 32]);
  GLDS(bsrc1 + 32, &Bs[1][(nb0 + 16) * 32]);
#pragma unroll
  for (int rr = 0; rr < 2; ++rr) {
    short8 pk = cvt8(a_pre[rr * 2 + 0], a_pre[rr * 2 + 1]);
    *(short8*)&As[0][(arow + rr * 64) * 40 + acol] = pk;
  }
  // B(0) must be landed; B(1) (newest 2 VMEM) may stay in flight.
  asm volatile("s_waitcnt vmcnt(2) lgkmcnt(0)" ::: "memory");
  __builtin_amdgcn_s_barrier();

  // ---- main K loop: fully unrolled, counted-vmcnt barriers ----
#pragma unroll
  for (int ks = 0; ks < 16; ++ks) {
    const int cur3 = ks % 3;   // Bs buffer read this step
    const int cur2 = ks & 1;   // As buffer read this step

    // issue A loads for ks+1 FIRST (older in vmcnt FIFO than B(ks+2), so the
    // compiler's counted wait before cvt also proves B(ks+1) complete)
    if (ks < 15) {
      const int k1 = (ks + 1) * 32;
#pragma unroll
      for (int rr = 0; rr < 2; ++rr) {
        a_pre[rr * 2 + 0] = *(const float4*)(aptr + rr * 64 * F_ + k1);
        a_pre[rr * 2 + 1] = *(const float4*)(aptr + rr * 64 * F_ + k1 + 4);
      }
    }
    // issue B gload_lds for ks+2 (lands by end of step ks+1; in flight across
    // THIS step's barrier — the whole point)
    if (ks < 14) {
      const int nb3 = (ks + 2) % 3;
      const int k2 = (ks + 2) * 32;
      GLDS(bsrc0 + k2, &Bs[nb3][nb0 * 32]);
      GLDS(bsrc1 + k2, &Bs[nb3][(nb0 + 16) * 32]);
    }

    short8 af[4], bfr[4];
#pragma unroll
    for (int i = 0; i < 4; i++)
      af[i] = *(const short8*)&As[cur2][(wm * 64 + i * 16 + l16) * 40 + quad * 8];
#pragma unroll
    for (int j = 0; j < 4; j++)
      bfr[j] = *(const short8*)&Bs[cur3][(wn * 64 + j * 16 + l16) * 32 +
                                         ((quad ^ ((l16 >> 1) & 3)) * 8)];
#pragma unroll
    for (int i = 0; i < 4; i++)
#pragma unroll
      for (int j = 0; j < 4; j++)
        acc[i][j] = __builtin_amdgcn_mfma_f32_16x16x32_bf16(af[i], bfr[j], acc[i][j], 0, 0, 0);

    if (ks < 15) {
      // compiler inserts counted vmcnt here for a_pre (leaves B(ks+2) in flight)
#pragma unroll
      for (int rr = 0; rr < 2; ++rr) {
        short8 pk = cvt8(a_pre[rr * 2 + 0], a_pre[rr * 2 + 1]);
        *(short8*)&As[cur2 ^ 1][(arow + rr * 64) * 40 + acol] = pk;
      }
    }

    // publish: ds_writes drained; vmcnt counted, NOT zero (except tail)
    if (ks < 14) {
      asm volatile("s_waitcnt vmcnt(2) lgkmcnt(0)" ::: "memory");
      __builtin_amdgcn_s_barrier();
    } else if (ks == 14) {
      asm volatile("s_waitcnt vmcnt(0) lgkmcnt(0)" ::: "memory");
      __builtin_amdgcn_s_barrier();
    }
  }
#undef GLDS

  // epilogue: C/D layout col=lane&15, row=quad*4+reg (m89/m91-verified)
  const int b = m_blk >> 5;  // 32 m-tiles per batch row (T/128)
  float w2v[4], vv[4];
#pragma unroll
  for (int j = 0; j < 4; j++) {
    const int h = n_blk * 128 + wn * 64 + j * 16 + l16;
    w2v[j] = w2d[b * H_ + h];
    vv[j] = V[h];
  }
  float rs[4][4];
#pragma unroll
  for (int i = 0; i < 4; i++)
#pragma unroll
    for (int r = 0; r < 4; r++) {
      float s = 0.f;
#pragma unroll
      for (int j = 0; j < 4; j++) s += tanh_fast(acc[i][j][r] + w2v[j]) * vv[j];
      rs[i][r] = s;
    }
#pragma unroll
  for (int i = 0; i < 4; i++)
#pragma unroll
    for (int r = 0; r < 4; r++) {
      float s = rs[i][r];
      s += __shfl_xor(s, 1, 16);
      s += __shfl_xor(s, 2, 16);
      s += __shfl_xor(s, 4, 16);
      s += __shfl_xor(s, 8, 16);
      rs[i][r] = s;
    }
  if (l16 == 0) {
#pragma unroll
    for (int i = 0; i < 4; i++)
#pragma unroll
      for (int r = 0; r < 4; r++)
        atomicAdd(&scores[m_blk * 128 + wm * 64 + i * 16 + quad * 4 + r], rs[i][r]);
  }
}

// ---- softmax over T per batch row ----
__global__ __launch_bounds__(256) void softmax_rows(const float* __restrict__ scores,
                                                    float* __restrict__ out) {
  const int b = blockIdx.x;
  const int tid = threadIdx.x;
  const int wave = tid >> 6;
  __shared__ float red[4];
  float v[16];
  float mx = -1e30f;
#pragma unroll
  for (int i = 0; i < 16; i++) {
    v[i] = scores[b * T_ + i * 256 + tid];
    mx = fmaxf(mx, v[i]);
  }
#pragma unroll
  for (int o = 32; o > 0; o >>= 1) mx = fmaxf(mx, __shfl_xor(mx, o, 64));
  if ((tid & 63) == 0) red[wave] = mx;
  __syncthreads();
  mx = fmaxf(fmaxf(red[0], red[1]), fmaxf(red[2], red[3]));
  __syncthreads();
  float sum = 0.f;
#pragma unroll
  for (int i = 0; i < 16; i++) {
    v[i] = __expf(v[i] - mx);
    sum += v[i];
  }
#pragma unroll
  for (int o = 32; o > 0; o >>= 1) sum += __shfl_xor(sum, o, 64);
  if ((tid & 63) == 0) red[wave] = sum;
  __syncthreads();
  sum = (red[0] + red[1]) + (red[2] + red[3]);
  const float inv = 1.0f / sum;
#pragma unroll
  for (int i = 0; i < 16; i++) out[b * T_ + i * 256 + tid] = v[i] * inv;
}

extern "C" void kernel_launch(void* const* d_in, const int* in_sizes, int n_in,
                              void* d_out, int out_size, void* d_ws, size_t ws_size,
                              hipStream_t stream) {
  const float* enc = (const float*)d_in[0];  // [B,T,F]
  const float* dec = (const float*)d_in[1];  // [B,F]
  const float* W1 = (const float*)d_in[2];   // [F,H]
  const float* W2 = (const float*)d_in[3];   // [F,H]
  const float* V = (const float*)d_in[4];    // [H,1]
  float* out = (float*)d_out;                // [B,T]

  char* ws = (char*)d_ws;
  float* scores = (float*)ws;                            // 512 KB
  unsigned short* W1T = (unsigned short*)(ws + 524288);  // 512 KB
  float* w2d = (float*)(ws + 1048576);                   // 64 KB

  (void)in_sizes; (void)n_in; (void)out_size; (void)ws_size;

  prep_all<<<dim3(288), dim3(1024), 0, stream>>>(W1, W1T, dec, W2, w2d, scores);
  fused_score<<<dim3(4096), dim3(256), 0, stream>>>(enc, W1T, w2d, V, scores);
  softmax_rows<<<dim3(32), dim3(256), 0, stream>>>(scores, out);
}

// Round 5
// 477.635 us; speedup vs baseline: 1.0746x; 1.0746x over previous
//
#include <hip/hip_runtime.h>
#include <hip/hip_bf16.h>

#define B_ 32
#define T_ 4096
#define F_ 512
#define H_ 512

typedef float floatx4 __attribute__((ext_vector_type(4)));
typedef short short8 __attribute__((ext_vector_type(8)));

__device__ __forceinline__ unsigned short f2bf16(float a) {
  unsigned ua = __float_as_uint(a);
  return (unsigned short)((ua + 0x7FFFu + ((ua >> 16) & 1u)) >> 16);
}

// tanh(x) = 1 - 2/(e^{2x}+1); graceful at +/-inf.
__device__ __forceinline__ float tanh_fast(float x) {
  float e = __expf(2.0f * x);
  return 1.0f - __fdividef(2.0f, e + 1.0f);
}

// 8x fp32 -> 8x bf16 (RNE) via compiler-fused v_cvt_pk_bf16_f32 (m240).
__device__ __forceinline__ short8 cvt8(float4 lo, float4 hi) {
  union { short8 s8; __hip_bfloat16 h[8]; } u;
  u.h[0] = __float2bfloat16(lo.x);
  u.h[1] = __float2bfloat16(lo.y);
  u.h[2] = __float2bfloat16(lo.z);
  u.h[3] = __float2bfloat16(lo.w);
  u.h[4] = __float2bfloat16(hi.x);
  u.h[5] = __float2bfloat16(hi.y);
  u.h[6] = __float2bfloat16(hi.z);
  u.h[7] = __float2bfloat16(hi.w);
  return u.s8;
}

// ---- merged prep: W1 transpose->bf16 + w2d = dec@W2 + scores=0 (one dispatch)
__global__ __launch_bounds__(1024) void prep_all(const float* __restrict__ W1,
                                                 unsigned short* __restrict__ W1T,
                                                 const float* __restrict__ dec,
                                                 const float* __restrict__ W2,
                                                 float* __restrict__ w2d,
                                                 float* __restrict__ scores) {
  __shared__ float tile[32][33];
  if (blockIdx.x < 256) {
    const int tx = threadIdx.x & 31, ty = threadIdx.x >> 5;
    const int bx = blockIdx.x & 15, by = blockIdx.x >> 4;
    const int f = by * 32 + ty;
    const int h = bx * 32 + tx;
    tile[ty][tx] = W1[f * H_ + h];
    __syncthreads();
    const int ho = bx * 32 + ty;
    const int fo = by * 32 + tx;
    W1T[ho * F_ + fo] = f2bf16(tile[tx][ty]);
  } else if (blockIdx.x < 272) {
    const int g = (blockIdx.x - 256) * 1024 + threadIdx.x;  // 16 blocks * 1024
    const int b = g >> 9;
    const int h = g & 511;
    float s0 = 0.f, s1 = 0.f, s2 = 0.f, s3 = 0.f;
    for (int f = 0; f < F_; f += 4) {
      s0 += dec[b * F_ + f + 0] * W2[(f + 0) * H_ + h];
      s1 += dec[b * F_ + f + 1] * W2[(f + 1) * H_ + h];
      s2 += dec[b * F_ + f + 2] * W2[(f + 2) * H_ + h];
      s3 += dec[b * F_ + f + 3] * W2[(f + 3) * H_ + h];
    }
    w2d[b * H_ + h] = (s0 + s1) + (s2 + s3);
  } else {
    const int g = (blockIdx.x - 272) * 1024 + threadIdx.x;
    const float4 z = {0.f, 0.f, 0.f, 0.f};
    ((float4*)scores)[g * 2 + 0] = z;
    ((float4*)scores)[g * 2 + 1] = z;
  }
}

// ---- main: fused (enc@W1) -> tanh(+w2d) -> .V row-reduce -> atomic scores ----
// Round-5 structure: UNIFORM 2-step-deep pipeline.
//  - A: global->VGPR issued at step ks for ks+2 (two parity register sets),
//    cvt_pk + ds_write of A(ks+1) at end of step ks. Every A load has a full
//    step of latency budget. Per-step asm "memory" barriers pin loads inside
//    their step (round-2 lesson: unfenced register pipelines get sunk).
//  - B: global_load_lds for ks+2 into Bs[(ks+2)%3], landed by barrier of ks+1.
//  - Barriers use COUNTED vmcnt(6) = A(ks+2)x4 + B(ks+2)x2 in flight; never
//    drain to 0 until the tail (T4).
//  - Both As and Bs use 32-short rows with XOR chunk swizzle
//    (slot = chunk ^ ((row>>1)&3)): write/read conflict-at-floor, no padding.
//    (Round-4 PMC: the 80B-padded As was the remaining 8.4M conflict cycles.)
//  - LDS 2x8KB As + 3x8KB Bs = 40960B -> 4 blocks/CU (160KB exactly).
// XCD-swizzled grid: xcd = bid&7; i = bid>>3; n_blk = i&3; m_blk = xcd + 8*(i>>2)
__global__ __launch_bounds__(256, 4) void fused_score(
    const float* __restrict__ enc, const unsigned short* __restrict__ W1T,
    const float* __restrict__ w2d, const float* __restrict__ V,
    float* __restrict__ scores) {
  __shared__ __align__(16) unsigned short As[2][128 * 32];
  __shared__ __align__(16) unsigned short Bs[3][128 * 32];

  const int tid = threadIdx.x;
  const int bid = blockIdx.x;
  const int xcd = bid & 7;
  const int ii = bid >> 3;
  const int n_blk = ii & 3;
  const int m_blk = xcd + ((ii >> 2) << 3);
  const int lane = tid & 63;
  const int wave = tid >> 6;
  const int wm = wave >> 1;
  const int wn = wave & 1;
  const int quad = lane >> 4;
  const int l16 = lane & 15;

  // A staging: thread covers chunk (tid&3) of rows {arow, arow+64}
  const int arow = tid >> 2;      // 0..63
  const int achk = tid & 3;       // 16B chunk within 128B k-slab
  const float* aptr = enc + (size_t)(m_blk * 128 + arow) * F_ + achk * 8;
  // swizzled LDS slot for As writes: chunk ^ ((row>>1)&3); rows arow & arow+64
  // share the swizzle ((r+64)>>1 & 3 == (r>>1)&3).
  const int aslot = (achk ^ ((arow >> 1) & 3)) * 8;

  // B staging via global_load_lds: dst wave-uniform base + lane*16B (linear).
  // Source pre-swizzled: LDS slot s of row n holds chunk s ^ ((n>>1)&3).
  const int nb0 = wave * 32;
  const int bl_n = lane >> 2;
  const int bl_c = (lane & 3) ^ ((lane >> 3) & 3);
  const unsigned short* bsrc0 =
      W1T + (size_t)(n_blk * 128 + nb0 + bl_n) * F_ + bl_c * 8;
  const unsigned short* bsrc1 = bsrc0 + 16 * F_;

  floatx4 acc[4][4];
#pragma unroll
  for (int i = 0; i < 4; i++)
#pragma unroll
    for (int j = 0; j < 4; j++) acc[i][j] = (floatx4){0.f, 0.f, 0.f, 0.f};

  // two parity-alternating A register sets: a_pre[k&1] holds A(k)
  float4 a_pre[2][4];

#define GLDS(SRC, DST)                                                       \
  __builtin_amdgcn_global_load_lds(                                          \
      (const __attribute__((address_space(1))) void*)(SRC),                  \
      (__attribute__((address_space(3))) void*)(DST), 16, 0, 0)

#define A_ISSUE(PAR, K)                                                      \
  do {                                                                       \
    a_pre[PAR][0] = *(const float4*)(aptr + (K));                            \
    a_pre[PAR][1] = *(const float4*)(aptr + (K) + 4);                        \
    a_pre[PAR][2] = *(const float4*)(aptr + 64 * F_ + (K));                  \
    a_pre[PAR][3] = *(const float4*)(aptr + 64 * F_ + (K) + 4);              \
  } while (0)

#define A_WRITE(PAR, BUF)                                                    \
  do {                                                                       \
    short8 pk0 = cvt8(a_pre[PAR][0], a_pre[PAR][1]);                         \
    short8 pk1 = cvt8(a_pre[PAR][2], a_pre[PAR][3]);                         \
    *(short8*)&As[BUF][arow * 32 + aslot] = pk0;                             \
    *(short8*)&As[BUF][(arow + 64) * 32 + aslot] = pk1;                      \
  } while (0)

#define B_ISSUE(BUF, K)                                                      \
  do {                                                                       \
    GLDS(bsrc0 + (K), &Bs[BUF][nb0 * 32]);                                   \
    GLDS(bsrc1 + (K), &Bs[BUF][(nb0 + 16) * 32]);                            \
  } while (0)

  // ---- prologue: A(0)->regs, B(0),B(1)->LDS, A(1)->regs, A(0)->As[0] ----
  A_ISSUE(0, 0);
  B_ISSUE(0, 0);
  B_ISSUE(1, 32);
  A_ISSUE(1, 32);
  A_WRITE(0, 0);  // compiler inserts counted vmcnt for A(0) only
  // need B(0) landed; leave [A(1)x4, B(1)x2] = 6 in flight
  asm volatile("s_waitcnt vmcnt(6) lgkmcnt(0)" ::: "memory");
  __builtin_amdgcn_s_barrier();

  // ---- main K loop: fully unrolled; steady state issues ks+2, computes ks,
  //      stages A(ks+1) into LDS, barrier leaves 6 VMEM in flight ----
#pragma unroll
  for (int ks = 0; ks < 16; ++ks) {
    if (ks <= 13) {
      A_ISSUE(ks & 1, (ks + 2) * 32);       // A(ks+2): parity ks (A(ks) is dead)
      B_ISSUE((ks + 2) % 3, (ks + 2) * 32); // B(ks+2)
    }

    short8 af[4], bfr[4];
#pragma unroll
    for (int i = 0; i < 4; i++)
      af[i] = *(const short8*)&As[ks & 1][(wm * 64 + i * 16 + l16) * 32 +
                                          ((quad ^ ((l16 >> 1) & 3)) * 8)];
#pragma unroll
    for (int j = 0; j < 4; j++)
      bfr[j] = *(const short8*)&Bs[ks % 3][(wn * 64 + j * 16 + l16) * 32 +
                                           ((quad ^ ((l16 >> 1) & 3)) * 8)];
#pragma unroll
    for (int i = 0; i < 4; i++)
#pragma unroll
      for (int j = 0; j < 4; j++)
        acc[i][j] = __builtin_amdgcn_mfma_f32_16x16x32_bf16(af[i], bfr[j], acc[i][j], 0, 0, 0);

    if (ks <= 14) {
      // stage A(ks+1) (loaded a full step ago) into the other As buffer
      A_WRITE((ks + 1) & 1, (ks + 1) & 1);
    }

    if (ks <= 13) {
      // keep A(ks+2)x4 + B(ks+2)x2 in flight across the barrier
      asm volatile("s_waitcnt vmcnt(6) lgkmcnt(0)" ::: "memory");
      __builtin_amdgcn_s_barrier();
    } else if (ks == 14) {
      asm volatile("s_waitcnt vmcnt(0) lgkmcnt(0)" ::: "memory");
      __builtin_amdgcn_s_barrier();
    }
  }
#undef GLDS
#undef A_ISSUE
#undef A_WRITE
#undef B_ISSUE

  // epilogue: C/D layout col=lane&15, row=quad*4+reg (m89/m91-verified)
  const int b = m_blk >> 5;  // 32 m-tiles per batch row (T/128)
  float w2v[4], vv[4];
#pragma unroll
  for (int j = 0; j < 4; j++) {
    const int h = n_blk * 128 + wn * 64 + j * 16 + l16;
    w2v[j] = w2d[b * H_ + h];
    vv[j] = V[h];
  }
  float rs[4][4];
#pragma unroll
  for (int i = 0; i < 4; i++)
#pragma unroll
    for (int r = 0; r < 4; r++) {
      float s = 0.f;
#pragma unroll
      for (int j = 0; j < 4; j++) s += tanh_fast(acc[i][j][r] + w2v[j]) * vv[j];
      rs[i][r] = s;
    }
#pragma unroll
  for (int i = 0; i < 4; i++)
#pragma unroll
    for (int r = 0; r < 4; r++) {
      float s = rs[i][r];
      s += __shfl_xor(s, 1, 16);
      s += __shfl_xor(s, 2, 16);
      s += __shfl_xor(s, 4, 16);
      s += __shfl_xor(s, 8, 16);
      rs[i][r] = s;
    }
  if (l16 == 0) {
#pragma unroll
    for (int i = 0; i < 4; i++)
#pragma unroll
      for (int r = 0; r < 4; r++)
        atomicAdd(&scores[m_blk * 128 + wm * 64 + i * 16 + quad * 4 + r], rs[i][r]);
  }
}

// ---- softmax over T per batch row ----
__global__ __launch_bounds__(256) void softmax_rows(const float* __restrict__ scores,
                                                    float* __restrict__ out) {
  const int b = blockIdx.x;
  const int tid = threadIdx.x;
  const int wave = tid >> 6;
  __shared__ float red[4];
  float v[16];
  float mx = -1e30f;
#pragma unroll
  for (int i = 0; i < 16; i++) {
    v[i] = scores[b * T_ + i * 256 + tid];
    mx = fmaxf(mx, v[i]);
  }
#pragma unroll
  for (int o = 32; o > 0; o >>= 1) mx = fmaxf(mx, __shfl_xor(mx, o, 64));
  if ((tid & 63) == 0) red[wave] = mx;
  __syncthreads();
  mx = fmaxf(fmaxf(red[0], red[1]), fmaxf(red[2], red[3]));
  __syncthreads();
  float sum = 0.f;
#pragma unroll
  for (int i = 0; i < 16; i++) {
    v[i] = __expf(v[i] - mx);
    sum += v[i];
  }
#pragma unroll
  for (int o = 32; o > 0; o >>= 1) sum += __shfl_xor(sum, o, 64);
  if ((tid & 63) == 0) red[wave] = sum;
  __syncthreads();
  sum = (red[0] + red[1]) + (red[2] + red[3]);
  const float inv = 1.0f / sum;
#pragma unroll
  for (int i = 0; i < 16; i++) out[b * T_ + i * 256 + tid] = v[i] * inv;
}

extern "C" void kernel_launch(void* const* d_in, const int* in_sizes, int n_in,
                              void* d_out, int out_size, void* d_ws, size_t ws_size,
                              hipStream_t stream) {
  const float* enc = (const float*)d_in[0];  // [B,T,F]
  const float* dec = (const float*)d_in[1];  // [B,F]
  const float* W1 = (const float*)d_in[2];   // [F,H]
  const float* W2 = (const float*)d_in[3];   // [F,H]
  const float* V = (const float*)d_in[4];    // [H,1]
  float* out = (float*)d_out;                // [B,T]

  char* ws = (char*)d_ws;
  float* scores = (float*)ws;                            // 512 KB
  unsigned short* W1T = (unsigned short*)(ws + 524288);  // 512 KB
  float* w2d = (float*)(ws + 1048576);                   // 64 KB

  (void)in_sizes; (void)n_in; (void)out_size; (void)ws_size;

  prep_all<<<dim3(288), dim3(1024), 0, stream>>>(W1, W1T, dec, W2, w2d, scores);
  fused_score<<<dim3(4096), dim3(256), 0, stream>>>(enc, W1T, w2d, V, scores);
  softmax_rows<<<dim3(32), dim3(256), 0, stream>>>(scores, out);
}